// Round 5
// baseline (2629.400 us; speedup 1.0000x reference)
//
#include <hip/hip_runtime.h>
#include <stdint.h>

#define BATCH 512
#define D_IN  2048
#define D_MCB 16000
#define N_OUT 3000
#define NSLOT 2000          // D_MCB / 8

typedef __bf16    bf16x8 __attribute__((ext_vector_type(8)));
typedef __bf16    bf16x4 __attribute__((ext_vector_type(4)));
typedef float     f32x4  __attribute__((ext_vector_type(4)));
typedef _Float16  h16x8  __attribute__((ext_vector_type(8)));

// Native LDS float atomic add (fire-and-forget). addr = 32-bit LDS byte addr.
__device__ __forceinline__ void lds_fadd(unsigned addr, float v) {
    asm volatile("ds_add_f32 %0, %1" :: "v"(addr), "v"(v) : "memory");
}

// 64 MACs: zacc[q] += a1 * f16(window elem q+D). One v_fma_mix_f32 per MAC:
// S0 = f16 half of window dword (op_sel picks lo/hi), S1 = fp32 a1, S2 = acc.
template<int D>
__device__ __forceinline__ void mix64(float* zacc, const unsigned* w, float a1) {
#pragma unroll
    for (int q = 0; q < 64; ++q) {
        const int e = q + D;           // constant after unroll
        if (e & 1)
            asm("v_fma_mix_f32 %0, %1, %2, %0 op_sel:[1,0,0] op_sel_hi:[1,0,0]"
                : "+v"(zacc[q]) : "v"(w[e >> 1]), "v"(a1));
        else
            asm("v_fma_mix_f32 %0, %1, %2, %0 op_sel:[0,0,0] op_sel_hi:[1,0,0]"
                : "+v"(zacc[q]) : "v"(w[e >> 1]), "v"(a1));
    }
}

// ---------------------------------------------------------------------------
// Prep (once per launch, 1 block): bin i's by coarse shift slot g = s>>3,
// s = (16000 - h1[i]) mod 16000. Emits meta[r] = (i<<3)|delta grouped by slot
// (r ordered by slot via prefix sum) and cnt8[g] = per-slot counts.
// ---------------------------------------------------------------------------
__global__ __launch_bounds__(256) void mcb_prep_kernel(
    const int* __restrict__ h1,
    unsigned* __restrict__ meta, unsigned char* __restrict__ cnt8)
{
    __shared__ int cnt[2048];
    __shared__ int scan[2048];
    __shared__ int cursor[2048];
    const int t = threadIdx.x;

    for (int g = t; g < 2048; g += 256) cnt[g] = 0;
    __syncthreads();
    for (int i = t; i < D_IN; i += 256) {
        int s = D_MCB - h1[i]; if (s >= D_MCB) s -= D_MCB;
        atomicAdd(&cnt[s >> 3], 1);
    }
    __syncthreads();
    for (int g = t; g < 2048; g += 256) scan[g] = cnt[g];
    __syncthreads();
    for (int off = 1; off < 2048; off <<= 1) {      // Hillis-Steele inclusive
        int v[8];
#pragma unroll
        for (int m = 0; m < 8; ++m) {
            int g = t + 256 * m;
            v[m] = scan[g] + ((g >= off) ? scan[g - off] : 0);
        }
        __syncthreads();
#pragma unroll
        for (int m = 0; m < 8; ++m) scan[t + 256 * m] = v[m];
        __syncthreads();
    }
    for (int g = t; g < 2048; g += 256) cursor[g] = scan[g] - cnt[g]; // exclusive
    __syncthreads();
    for (int i = t; i < D_IN; i += 256) {
        int s = D_MCB - h1[i]; if (s >= D_MCB) s -= D_MCB;
        int g = s >> 3, d = s & 7;
        int r = atomicAdd(&cursor[g], 1);
        meta[r] = ((unsigned)i << 3) | (unsigned)d;
    }
    for (int g = t; g < NSLOT; g += 256) cnt8[g] = (unsigned char)cnt[g];
}

// ---------------------------------------------------------------------------
// Conv kernel: z[b,k] = sum_i a1[b,i] * p2[b,(k+s_i)%d] via sorted slot-walk.
// R4 lesson: 9 b128/i had LDS pipe AND VALU co-bound at ~1.5 ms. Now: f16 p2
// table (XOR-swizzled 16B chunks), rolling 36-dword register window advanced
// 1 chunk/slot (1 b128/slot), v_fma_mix_f32 = 1 inst/MAC, no unpack.
// LDS: 64K table(f16 x32768, fp32 p2 overlay at build) + 8K a1(delta in low
// 3 mantissa bits) + 2K counts = 75776 B -> 2 blocks/CU.
// ---------------------------------------------------------------------------
__global__ __launch_bounds__(256, 2) void mcb_conv_kernel(
    const float* __restrict__ x0, const float* __restrict__ x1,
    const float* __restrict__ s1, const float* __restrict__ s2,
    const int* __restrict__ h2,
    const unsigned* __restrict__ meta, const unsigned char* __restrict__ cnt8,
    __bf16* __restrict__ zb)
{
    __shared__ __align__(16) char smem[75776];
    float*          p2f = (float*)smem;                    // [16000] build overlay
    const uint4*    tab = (const uint4*)smem;              // [4096] f16 chunks
    unsigned*       afb = (unsigned*)(smem + 65536);       // [2048] a1|delta
    unsigned char*  cs8 = (unsigned char*)(smem + 73728);  // [2000]

    const int b    = blockIdx.x;
    const int t    = threadIdx.x;
    const int lane = t & 63;
    const int wave = t >> 6;

    // --- phase 1: zero p2, stage a1 (sorted order, delta bit-stolen), counts ---
    for (int k = t; k < D_MCB; k += 256) p2f[k] = 0.0f;
    for (int r = t; r < D_IN; r += 256) {
        unsigned m = meta[r];
        int i = (int)(m >> 3);
        float a1 = s1[i] * x0[b * D_IN + i];
        afb[r] = (__float_as_uint(a1) & 0xfffffff8u) | (m & 7u);
    }
    for (int g = t; g < NSLOT; g += 256) cs8[g] = cnt8[g];
    __syncthreads();

    // --- phase 2: scatter p2 (2048 LDS atomics, cheap) ---
    for (int j = t; j < D_IN; j += 256) {
        float a2 = s2[j] * x1[b * D_IN + j];
        lds_fadd((unsigned)(uintptr_t)&p2f[h2[j]], a2);
    }
    __syncthreads();

    // --- phase 3: fp32 p2 -> f16 table, replicated to 32768, XOR-swizzled at
    //     16B chunks (phys = c ^ ((c>>3)&7)); register-staged (overlay-safe) ---
    uint4 stage[16];
#pragma unroll
    for (int m = 0; m < 16; ++m) {
        int c  = t + 256 * m;                  // chunk in [0,4096)
        int e8 = c << 3;                       // elem base in [0,32768)
        if (e8 >= 2 * D_MCB) e8 -= 2 * D_MCB;
        else if (e8 >= D_MCB) e8 -= D_MCB;
        f32x4 lo = *(const f32x4*)(p2f + e8);
        f32x4 hi = *(const f32x4*)(p2f + e8 + 4);
        h16x8 o;
#pragma unroll
        for (int q = 0; q < 4; ++q) { o[q] = (_Float16)lo[q]; o[q + 4] = (_Float16)hi[q]; }
        stage[m] = *(uint4*)&o;
    }
    __syncthreads();
#pragma unroll
    for (int m = 0; m < 16; ++m) {
        int c = t + 256 * m;
        ((uint4*)smem)[c ^ ((c >> 3) & 7)] = stage[m];
    }
    __syncthreads();

    // --- phase 4: slot-walk gather. Lane owns k in [k0,k0+64); wave w covers
    //     [4000w, 4000w+4096), overlap masked at store. Window = 9 chunks
    //     (36 dwords of f16 pairs) = elems [8(K8+g), 8(K8+g)+72). ---
    const int k0 = wave * 4000 + (lane << 6);
    const int K8 = k0 >> 3;

    float zacc[64];
#pragma unroll
    for (int q = 0; q < 64; ++q) zacc[q] = 0.f;

    unsigned w[36];
#pragma unroll
    for (int tt = 0; tt < 9; ++tt) {
        int c = K8 + tt;
        uint4 v = tab[c ^ ((c >> 3) & 7)];
        w[4 * tt] = v.x; w[4 * tt + 1] = v.y; w[4 * tt + 2] = v.z; w[4 * tt + 3] = v.w;
    }

    int r = 0;
    for (int g = 0; g < NSLOT; ++g) {
        int cpre = K8 + g + 9;                          // prefetch next top chunk
        uint4 tnext = tab[cpre ^ ((cpre >> 3) & 7)];

        int cv = cs8[g];                                // wave-uniform
        for (int e = 0; e < cv; ++e, ++r) {
            unsigned ab = afb[r];                       // broadcast ds_read_b32
            float a1 = __uint_as_float(ab & 0xfffffff8u);
            switch (ab & 7u) {
                case 0: mix64<0>(zacc, w, a1); break;
                case 1: mix64<1>(zacc, w, a1); break;
                case 2: mix64<2>(zacc, w, a1); break;
                case 3: mix64<3>(zacc, w, a1); break;
                case 4: mix64<4>(zacc, w, a1); break;
                case 5: mix64<5>(zacc, w, a1); break;
                case 6: mix64<6>(zacc, w, a1); break;
                default: mix64<7>(zacc, w, a1); break;
            }
        }
#pragma unroll
        for (int q = 0; q < 32; ++q) w[q] = w[q + 4];   // advance 1 chunk
        w[32] = tnext.x; w[33] = tnext.y; w[34] = tnext.z; w[35] = tnext.w;
    }

    // --- store bf16 z, masking wave overlap (all bounds % 8 == 0) ---
    const int klim = wave * 4000 + 4000;
#pragma unroll
    for (int g = 0; g < 8; ++g) {
        int kg = k0 + g * 8;
        if (kg < klim) {
            bf16x8 o;
#pragma unroll
            for (int e = 0; e < 8; ++e) o[e] = (__bf16)zacc[g * 8 + e];
            *(bf16x8*)(zb + (size_t)b * D_MCB + kg) = o;
        }
    }
}

// ---------------------------------------------------------------------------
// W fp32 -> bf16 pre-convert (one pass).
// ---------------------------------------------------------------------------
__global__ __launch_bounds__(256) void wconv_kernel(
    const float* __restrict__ W, __bf16* __restrict__ Wb)
{
    size_t i = ((size_t)blockIdx.x * 256 + threadIdx.x) * 4;
    f32x4 w = *(const f32x4*)(W + i);
    bf16x4 o;
#pragma unroll
    for (int q = 0; q < 4; ++q) o[q] = (__bf16)w[q];
    *(bf16x4*)(Wb + i) = o;
}

// ---------------------------------------------------------------------------
// GEMM (fast path): out = relu(z @ Wb^T + bias), bf16 MFMA 16x16x32.
// ---------------------------------------------------------------------------
__global__ __launch_bounds__(256) void mcb_gemm_bf16_kernel(
    const __bf16* __restrict__ zbm, const __bf16* __restrict__ Wb,
    const float* __restrict__ bias, float* __restrict__ out)
{
    const int lane = threadIdx.x & 63;
    const int wave = threadIdx.x >> 6;
    const int wm = wave >> 1;
    const int wn = wave & 1;
    const int llo = lane & 15;
    const int lhi = lane >> 4;

    const int m0 = blockIdx.y * 64 + wm * 32;
    const int n0 = blockIdx.x * 64 + wn * 32;

    f32x4 acc[2][2] = {};

    const int arow0 = m0 + llo;
    const int bcol0 = n0 + llo;
    const int kk = lhi * 8;

    const __bf16* aptr0 = zbm + (size_t)arow0 * D_MCB + kk;
    const __bf16* aptr1 = aptr0 + (size_t)16 * D_MCB;
    const __bf16* bptr0 = Wb + (size_t)bcol0 * D_MCB + kk;
    const __bf16* bptr1 = bptr0 + (size_t)16 * D_MCB;
    const bool bok0 = (bcol0 < N_OUT);
    const bool bok1 = (bcol0 + 16 < N_OUT);

    for (int k = 0; k < D_MCB; k += 32) {
        bf16x8 a0 = *(const bf16x8*)(aptr0 + k);
        bf16x8 a1 = *(const bf16x8*)(aptr1 + k);
        bf16x8 b0 = {}, b1 = {};
        if (bok0) b0 = *(const bf16x8*)(bptr0 + k);
        if (bok1) b1 = *(const bf16x8*)(bptr1 + k);

        acc[0][0] = __builtin_amdgcn_mfma_f32_16x16x32_bf16(a0, b0, acc[0][0], 0, 0, 0);
        acc[0][1] = __builtin_amdgcn_mfma_f32_16x16x32_bf16(a0, b1, acc[0][1], 0, 0, 0);
        acc[1][0] = __builtin_amdgcn_mfma_f32_16x16x32_bf16(a1, b0, acc[1][0], 0, 0, 0);
        acc[1][1] = __builtin_amdgcn_mfma_f32_16x16x32_bf16(a1, b1, acc[1][1], 0, 0, 0);
    }

#pragma unroll
    for (int bn = 0; bn < 2; ++bn) {
        int col = bcol0 + bn * 16;
        if (col >= N_OUT) continue;
        float bv = bias[col];
#pragma unroll
        for (int am = 0; am < 2; ++am) {
            int rbase = m0 + am * 16 + lhi * 4;
#pragma unroll
            for (int r = 0; r < 4; ++r) {
                float v = acc[am][bn][r] + bv;
                out[(size_t)(rbase + r) * N_OUT + col] = v > 0.0f ? v : 0.0f;
            }
        }
    }
}

// ---------------------------------------------------------------------------
// GEMM (fallback): W stays fp32, converted in-register.
// ---------------------------------------------------------------------------
__global__ __launch_bounds__(256) void mcb_gemm_f32_kernel(
    const __bf16* __restrict__ zbm, const float* __restrict__ W,
    const float* __restrict__ bias, float* __restrict__ out)
{
    const int lane = threadIdx.x & 63;
    const int wave = threadIdx.x >> 6;
    const int wm = wave >> 1;
    const int wn = wave & 1;
    const int llo = lane & 15;
    const int lhi = lane >> 4;

    const int m0 = blockIdx.y * 64 + wm * 32;
    const int n0 = blockIdx.x * 64 + wn * 32;

    f32x4 acc[2][2] = {};

    const int arow0 = m0 + llo;
    const int bcol0 = n0 + llo;
    const int kk = lhi * 8;

    const __bf16* aptr0 = zbm + (size_t)arow0 * D_MCB + kk;
    const __bf16* aptr1 = aptr0 + (size_t)16 * D_MCB;
    const float*  bptr0 = W + (size_t)bcol0 * D_MCB + kk;
    const float*  bptr1 = bptr0 + (size_t)16 * D_MCB;
    const bool bok0 = (bcol0 < N_OUT);
    const bool bok1 = (bcol0 + 16 < N_OUT);

    for (int k = 0; k < D_MCB; k += 32) {
        bf16x8 a0 = *(const bf16x8*)(aptr0 + k);
        bf16x8 a1 = *(const bf16x8*)(aptr1 + k);

        bf16x8 b0 = {}, b1 = {};
        if (bok0) {
            f32x4 w0 = *(const f32x4*)(bptr0 + k);
            f32x4 w1 = *(const f32x4*)(bptr0 + k + 4);
#pragma unroll
            for (int q = 0; q < 4; ++q) { b0[q] = (__bf16)w0[q]; b0[q + 4] = (__bf16)w1[q]; }
        }
        if (bok1) {
            f32x4 w0 = *(const f32x4*)(bptr1 + k);
            f32x4 w1 = *(const f32x4*)(bptr1 + k + 4);
#pragma unroll
            for (int q = 0; q < 4; ++q) { b1[q] = (__bf16)w0[q]; b1[q + 4] = (__bf16)w1[q]; }
        }

        acc[0][0] = __builtin_amdgcn_mfma_f32_16x16x32_bf16(a0, b0, acc[0][0], 0, 0, 0);
        acc[0][1] = __builtin_amdgcn_mfma_f32_16x16x32_bf16(a0, b1, acc[0][1], 0, 0, 0);
        acc[1][0] = __builtin_amdgcn_mfma_f32_16x16x32_bf16(a1, b0, acc[1][0], 0, 0, 0);
        acc[1][1] = __builtin_amdgcn_mfma_f32_16x16x32_bf16(a1, b1, acc[1][1], 0, 0, 0);
    }

#pragma unroll
    for (int bn = 0; bn < 2; ++bn) {
        int col = bcol0 + bn * 16;
        if (col >= N_OUT) continue;
        float bv = bias[col];
#pragma unroll
        for (int am = 0; am < 2; ++am) {
            int rbase = m0 + am * 16 + lhi * 4;
#pragma unroll
            for (int r = 0; r < 4; ++r) {
                float v = acc[am][bn][r] + bv;
                out[(size_t)(rbase + r) * N_OUT + col] = v > 0.0f ? v : 0.0f;
            }
        }
    }
}

extern "C" void kernel_launch(void* const* d_in, const int* in_sizes, int n_in,
                              void* d_out, int out_size, void* d_ws, size_t ws_size,
                              hipStream_t stream) {
    // setup_inputs() order: x0, x1, s1, s2, W, b, h1, h2
    const float* x0   = (const float*)d_in[0];
    const float* x1   = (const float*)d_in[1];
    const float* s1   = (const float*)d_in[2];
    const float* s2   = (const float*)d_in[3];
    const float* W    = (const float*)d_in[4];
    const float* bias = (const float*)d_in[5];
    const int*   h1   = (const int*)d_in[6];
    const int*   h2   = (const int*)d_in[7];
    float* out = (float*)d_out;

    const size_t zb_bytes = (size_t)BATCH * D_MCB * sizeof(__bf16);   // 16,384,000
    const size_t wb_bytes = (size_t)N_OUT * D_MCB * sizeof(__bf16);   // 96,000,000
    const bool have_wb = (ws_size >= zb_bytes + wb_bytes + 8192 + 2048);

    __bf16*        zbm  = (__bf16*)d_ws;
    char*          tail = (char*)d_ws + zb_bytes + (have_wb ? wb_bytes : 0);
    unsigned*      meta = (unsigned*)tail;                 // 8192 B
    unsigned char* cnt8 = (unsigned char*)(tail + 8192);   // 2000 B

    mcb_prep_kernel<<<1, 256, 0, stream>>>(h1, meta, cnt8);
    mcb_conv_kernel<<<BATCH, 256, 0, stream>>>(x0, x1, s1, s2, h2, meta, cnt8, zbm);

    if (have_wb) {
        __bf16* Wb = (__bf16*)((char*)d_ws + zb_bytes);
        wconv_kernel<<<46875, 256, 0, stream>>>(W, Wb);
        mcb_gemm_bf16_kernel<<<dim3(47, 8), 256, 0, stream>>>(zbm, Wb, bias, out);
    } else {
        mcb_gemm_f32_kernel<<<dim3(47, 8), 256, 0, stream>>>(zbm, W, bias, out);
    }
}